// Round 3
// baseline (597.365 us; speedup 1.0000x reference)
//
#include <hip/hip_runtime.h>

#define F_IN 128
#define H1   16
#define C2   8
#define BSHIFT 7
#define BNODES 128            // nodes per bucket
#define MAXBUCK 1024          // LDS array bound (runtime nbuck=782)
#define NBLK 256              // blocks for binning passes

// ---------- pass 1: per-(bucket,block) destination-bucket histogram ----------
__global__ void binA_kernel(const int* __restrict__ col, int E, int chunk,
                            int nbuck, int* __restrict__ bbc) {
    __shared__ int h[MAXBUCK];
    for (int b = threadIdx.x; b < nbuck; b += blockDim.x) h[b] = 0;
    __syncthreads();
    int base = blockIdx.x * chunk;
    int lim = min(base + chunk, E);
    for (int e = base + threadIdx.x; e < lim; e += blockDim.x) {
        atomicAdd(&h[col[e] >> BSHIFT], 1);
    }
    __syncthreads();
    for (int b = threadIdx.x; b < nbuck; b += blockDim.x)
        bbc[b * NBLK + blockIdx.x] = h[b];
}

// ---------- exclusive scan over M = nbuck*NBLK values (3 kernels) ----------
__global__ void scanA_kernel(const int* __restrict__ in, int M,
                             int* __restrict__ outp, int* __restrict__ bsum) {
    __shared__ int s[256];
    int i = blockIdx.x * 256 + threadIdx.x;
    int v = (i < M) ? in[i] : 0;
    s[threadIdx.x] = v;
    __syncthreads();
    int incl = v;
    for (int off = 1; off < 256; off <<= 1) {
        int t = (threadIdx.x >= off) ? s[threadIdx.x - off] : 0;
        __syncthreads();
        incl += t;
        s[threadIdx.x] = incl;
        __syncthreads();
    }
    if (i < M) outp[i] = incl - v;
    if (threadIdx.x == 255) bsum[blockIdx.x] = incl;
}

__global__ void scanB_kernel(int* __restrict__ bsum, int* __restrict__ boff, int NB) {
    __shared__ int s[1024];
    int v = (threadIdx.x < NB) ? bsum[threadIdx.x] : 0;
    s[threadIdx.x] = v;
    __syncthreads();
    int incl = v;
    for (int off = 1; off < 1024; off <<= 1) {
        int t = (threadIdx.x >= off) ? s[threadIdx.x - off] : 0;
        __syncthreads();
        incl += t;
        s[threadIdx.x] = incl;
        __syncthreads();
    }
    boff[threadIdx.x] = incl - v;
}

__global__ void scanC_kernel(int* __restrict__ ptr, const int* __restrict__ boff, int M) {
    int i = blockIdx.x * 256 + threadIdx.x;
    if (i < M) ptr[i] += boff[blockIdx.x];
}

// ---------- pass 2: scatter packed records into bucket-major staging ----------
// record = (r << BSHIFT) | (c & (BNODES-1))
__global__ void binScatter_kernel(const int* __restrict__ ei, int E, int chunk,
                                  int nbuck, const int* __restrict__ bbcScan,
                                  int* __restrict__ stage) {
    __shared__ int cur[MAXBUCK];
    for (int b = threadIdx.x; b < nbuck; b += blockDim.x)
        cur[b] = bbcScan[b * NBLK + blockIdx.x];
    __syncthreads();
    int base = blockIdx.x * chunk;
    int lim = min(base + chunk, E);
    for (int e = base + threadIdx.x; e < lim; e += blockDim.x) {
        int r = ei[e];
        int c = ei[E + e];
        int p = atomicAdd(&cur[c >> BSHIFT], 1);
        stage[p] = (r << BSHIFT) | (c & (BNODES - 1));
    }
}

// ---------- per-bucket degree count -> dinv (fused) ----------
__global__ void degdinv_kernel(const int* __restrict__ stage, const int* __restrict__ bbcScan,
                               int E, int nbuck, float* __restrict__ dinv, int N) {
    __shared__ int deg[BNODES];
    int b = blockIdx.x;
    if (threadIdx.x < BNODES) deg[threadIdx.x] = 0;
    __syncthreads();
    int s = bbcScan[b * NBLK];
    int e_end = (b == nbuck - 1) ? E : bbcScan[(b + 1) * NBLK];
    for (int i = s + threadIdx.x; i < e_end; i += blockDim.x)
        atomicAdd(&deg[stage[i] & (BNODES - 1)], 1);
    __syncthreads();
    int v = b * BNODES + threadIdx.x;
    if (threadIdx.x < BNODES && v < N)
        dinv[v] = rsqrtf((float)deg[threadIdx.x] + 1.0f);
}

// ---------- h1s = (x @ W1) * dinv[v] ----------
__global__ void gemm1_kernel(const float* __restrict__ x, const float* __restrict__ W1,
                             const float* __restrict__ dinv, float* __restrict__ h1s, int N) {
    __shared__ float sW[F_IN * H1];
    for (int i = threadIdx.x; i < F_IN * H1; i += blockDim.x) sW[i] = W1[i];
    __syncthreads();
    int v = blockIdx.x * blockDim.x + threadIdx.x;
    if (v >= N) return;
    float acc[H1];
#pragma unroll
    for (int j = 0; j < H1; ++j) acc[j] = 0.0f;
    const float4* xr = reinterpret_cast<const float4*>(x + (size_t)v * F_IN);
#pragma unroll 8
    for (int k4 = 0; k4 < F_IN / 4; ++k4) {
        float4 xv = xr[k4];
        const float* w = &sW[k4 * 4 * H1];
#pragma unroll
        for (int j = 0; j < H1; ++j) acc[j] += xv.x * w[j];
#pragma unroll
        for (int j = 0; j < H1; ++j) acc[j] += xv.y * w[H1 + j];
#pragma unroll
        for (int j = 0; j < H1; ++j) acc[j] += xv.z * w[2 * H1 + j];
#pragma unroll
        for (int j = 0; j < H1; ++j) acc[j] += xv.w * w[3 * H1 + j];
    }
    float di = dinv[v];
    float4* ho = reinterpret_cast<float4*>(h1s + (size_t)v * H1);
#pragma unroll
    for (int q = 0; q < H1 / 4; ++q) {
        ho[q] = make_float4(acc[q * 4 + 0] * di, acc[q * 4 + 1] * di,
                            acc[q * 4 + 2] * di, acc[q * 4 + 3] * di);
    }
}

// ---------- layer-1 aggregation in LDS + relu + GEMM2 fused ----------
#define AGG1_PAD 17
__global__ void agg1_kernel(const int* __restrict__ stage, const int* __restrict__ bbcScan,
                            int E, int nbuck, const float* __restrict__ h1s,
                            const float* __restrict__ dinv, const float* __restrict__ b1,
                            const float* __restrict__ W2, float* __restrict__ h2s, int N) {
    __shared__ float agg[BNODES * AGG1_PAD];
    __shared__ float sW[H1 * C2];
    __shared__ float sb[H1];
    for (int i = threadIdx.x; i < BNODES * AGG1_PAD; i += blockDim.x) agg[i] = 0.0f;
    for (int i = threadIdx.x; i < H1 * C2; i += blockDim.x) sW[i] = W2[i];
    for (int i = threadIdx.x; i < H1; i += blockDim.x) sb[i] = b1[i];
    __syncthreads();

    int b = blockIdx.x;
    int base = b * BNODES;
    int s = bbcScan[b * NBLK];
    int e_end = (b == nbuck - 1) ? E : bbcScan[(b + 1) * NBLK];

    int f = threadIdx.x & 15;
    // 16 lanes per edge: lane f handles feature f
    for (int i = s + (threadIdx.x >> 4); i < e_end; i += (int)(blockDim.x >> 4)) {
        int rec = stage[i];
        int r = rec >> BSHIFT;
        int cl = rec & (BNODES - 1);
        float val = h1s[(size_t)r * H1 + f];
        atomicAdd(&agg[cl * AGG1_PAD + f], val);
    }
    __syncthreads();

    // finalize: relu(dinv*(agg + self) + b1), store back to LDS
    for (int vi = threadIdx.x >> 4; vi < BNODES; vi += (int)(blockDim.x >> 4)) {
        int v = base + vi;
        if (v < N) {
            float hv = dinv[v] * (agg[vi * AGG1_PAD + f] + h1s[(size_t)v * H1 + f]) + sb[f];
            agg[vi * AGG1_PAD + f] = fmaxf(hv, 0.0f);
        }
    }
    __syncthreads();

    // GEMM2: h2s[v] = (hrelu @ W2) * dinv[v]
    int j = threadIdx.x & 7;
    for (int vi = threadIdx.x >> 3; vi < BNODES; vi += (int)(blockDim.x >> 3)) {
        int v = base + vi;
        if (v < N) {
            float dot = 0.0f;
#pragma unroll
            for (int k = 0; k < H1; ++k) dot += agg[vi * AGG1_PAD + k] * sW[k * C2 + j];
            h2s[(size_t)v * C2 + j] = dot * dinv[v];
        }
    }
}

// ---------- layer-2 aggregation in LDS + bias + log_softmax fused ----------
#define AGG2_PAD 9
__global__ void agg2_kernel(const int* __restrict__ stage, const int* __restrict__ bbcScan,
                            int E, int nbuck, const float* __restrict__ h2s,
                            const float* __restrict__ dinv, const float* __restrict__ b2,
                            float* __restrict__ out, int N) {
    __shared__ float agg[BNODES * AGG2_PAD];
    __shared__ float sb[C2];
    for (int i = threadIdx.x; i < BNODES * AGG2_PAD; i += blockDim.x) agg[i] = 0.0f;
    if (threadIdx.x < C2) sb[threadIdx.x] = b2[threadIdx.x];
    __syncthreads();

    int b = blockIdx.x;
    int base = b * BNODES;
    int s = bbcScan[b * NBLK];
    int e_end = (b == nbuck - 1) ? E : bbcScan[(b + 1) * NBLK];

    int f = threadIdx.x & 7;
    // 8 lanes per edge
    for (int i = s + (threadIdx.x >> 3); i < e_end; i += (int)(blockDim.x >> 3)) {
        int rec = stage[i];
        int r = rec >> BSHIFT;
        int cl = rec & (BNODES - 1);
        float val = h2s[(size_t)r * C2 + f];
        atomicAdd(&agg[cl * AGG2_PAD + f], val);
    }
    __syncthreads();

    for (int vi = threadIdx.x >> 3; vi < BNODES; vi += (int)(blockDim.x >> 3)) {
        int v = base + vi;
        if (v < N) {
            float z = dinv[v] * (agg[vi * AGG2_PAD + f] + h2s[(size_t)v * C2 + f]) + sb[f];
            float m = z;
#pragma unroll
            for (int mask = 1; mask < 8; mask <<= 1)
                m = fmaxf(m, __shfl_xor(m, mask, 8));
            float ex = __expf(z - m);
            float ssum = ex;
#pragma unroll
            for (int mask = 1; mask < 8; mask <<= 1)
                ssum += __shfl_xor(ssum, mask, 8);
            float lse = m + logf(ssum);
            out[(size_t)v * C2 + f] = z - lse;
        }
    }
}

extern "C" void kernel_launch(void* const* d_in, const int* in_sizes, int n_in,
                              void* d_out, int out_size, void* d_ws, size_t ws_size,
                              hipStream_t stream) {
    const float* x  = (const float*)d_in[0];
    const int*   ei = (const int*)d_in[1];
    const float* W1 = (const float*)d_in[2];
    const float* b1 = (const float*)d_in[3];
    const float* W2 = (const float*)d_in[4];
    const float* b2 = (const float*)d_in[5];
    float* out = (float*)d_out;

    const int N = in_sizes[0] / F_IN;
    const int E = in_sizes[1] / 2;
    const int nbuck = (N + BNODES - 1) >> BSHIFT;        // 782
    const int M = nbuck * NBLK;                          // 200192
    const int chunk = (E + NBLK - 1) / NBLK;             // 12500

    // workspace layout (ints/floats, 4B each)
    int*   stage   = (int*)d_ws;                         // E
    int*   bbc     = stage + E;                          // M
    int*   bbcScan = bbc + M;                            // M
    int*   bsum    = bbcScan + M;                        // 1024
    int*   boff    = bsum + 1024;                        // 1024
    float* dinv    = (float*)(boff + 1024);              // N
    float* h1s     = dinv + N;                           // 16N
    float* h2s     = h1s + (size_t)16 * N;               // 8N

    const int TB = 256;
    const int scanBlocks = (M + 255) / 256;              // = nbuck

    binA_kernel<<<NBLK, TB, 0, stream>>>(ei + E, E, chunk, nbuck, bbc);
    scanA_kernel<<<scanBlocks, TB, 0, stream>>>(bbc, M, bbcScan, bsum);
    scanB_kernel<<<1, 1024, 0, stream>>>(bsum, boff, scanBlocks);
    scanC_kernel<<<scanBlocks, TB, 0, stream>>>(bbcScan, boff, M);
    binScatter_kernel<<<NBLK, TB, 0, stream>>>(ei, E, chunk, nbuck, bbcScan, stage);
    degdinv_kernel<<<nbuck, TB, 0, stream>>>(stage, bbcScan, E, nbuck, dinv, N);
    gemm1_kernel<<<(N + TB - 1) / TB, TB, 0, stream>>>(x, W1, dinv, h1s, N);
    agg1_kernel<<<nbuck, TB, 0, stream>>>(stage, bbcScan, E, nbuck, h1s, dinv, b1, W2, h2s, N);
    agg2_kernel<<<nbuck, TB, 0, stream>>>(stage, bbcScan, E, nbuck, h2s, dinv, b2, out, N);
}

// Round 4
// 585.938 us; speedup vs baseline: 1.0195x; 1.0195x over previous
//
#include <hip/hip_runtime.h>

#define F_IN 128
#define H1   16
#define C2   8
#define BSHIFT 7
#define BNODES 128            // nodes per bucket
#define MAXBUCK 1024          // LDS array bound (runtime nbuck=782)
#define NBLK 256              // blocks for binning passes

// ---------- pass 1: per-(bucket,block) destination-bucket histogram ----------
__global__ void binA_kernel(const int* __restrict__ col, int E, int chunk,
                            int nbuck, int* __restrict__ bbc) {
    __shared__ int h[MAXBUCK];
    for (int b = threadIdx.x; b < nbuck; b += blockDim.x) h[b] = 0;
    __syncthreads();
    int base = blockIdx.x * chunk;
    int lim = min(base + chunk, E);
    for (int e = base + threadIdx.x; e < lim; e += blockDim.x) {
        atomicAdd(&h[col[e] >> BSHIFT], 1);
    }
    __syncthreads();
    for (int b = threadIdx.x; b < nbuck; b += blockDim.x)
        bbc[b * NBLK + blockIdx.x] = h[b];
}

// ---------- exclusive scan over M = nbuck*NBLK values (3 kernels) ----------
__global__ void scanA_kernel(const int* __restrict__ in, int M,
                             int* __restrict__ outp, int* __restrict__ bsum) {
    __shared__ int s[256];
    int i = blockIdx.x * 256 + threadIdx.x;
    int v = (i < M) ? in[i] : 0;
    s[threadIdx.x] = v;
    __syncthreads();
    int incl = v;
    for (int off = 1; off < 256; off <<= 1) {
        int t = (threadIdx.x >= off) ? s[threadIdx.x - off] : 0;
        __syncthreads();
        incl += t;
        s[threadIdx.x] = incl;
        __syncthreads();
    }
    if (i < M) outp[i] = incl - v;
    if (threadIdx.x == 255) bsum[blockIdx.x] = incl;
}

__global__ void scanB_kernel(int* __restrict__ bsum, int* __restrict__ boff, int NB) {
    __shared__ int s[1024];
    int v = (threadIdx.x < NB) ? bsum[threadIdx.x] : 0;
    s[threadIdx.x] = v;
    __syncthreads();
    int incl = v;
    for (int off = 1; off < 1024; off <<= 1) {
        int t = (threadIdx.x >= off) ? s[threadIdx.x - off] : 0;
        __syncthreads();
        incl += t;
        s[threadIdx.x] = incl;
        __syncthreads();
    }
    boff[threadIdx.x] = incl - v;
}

__global__ void scanC_kernel(int* __restrict__ ptr, const int* __restrict__ boff, int M) {
    int i = blockIdx.x * 256 + threadIdx.x;
    if (i < M) ptr[i] += boff[blockIdx.x];
}

// ---------- pass 2: scatter packed records into bucket-major staging ----------
// record = (r << BSHIFT) | (c & (BNODES-1))
__global__ void binScatter_kernel(const int* __restrict__ ei, int E, int chunk,
                                  int nbuck, const int* __restrict__ bbcScan,
                                  int* __restrict__ stage) {
    __shared__ int cur[MAXBUCK];
    for (int b = threadIdx.x; b < nbuck; b += blockDim.x)
        cur[b] = bbcScan[b * NBLK + blockIdx.x];
    __syncthreads();
    int base = blockIdx.x * chunk;
    int lim = min(base + chunk, E);
    for (int e = base + threadIdx.x; e < lim; e += blockDim.x) {
        int r = ei[e];
        int c = ei[E + e];
        int p = atomicAdd(&cur[c >> BSHIFT], 1);
        stage[p] = (r << BSHIFT) | (c & (BNODES - 1));
    }
}

// ---------- per-bucket degree count -> dinv (fused) ----------
__global__ void degdinv_kernel(const int* __restrict__ stage, const int* __restrict__ bbcScan,
                               int E, int nbuck, float* __restrict__ dinv, int N) {
    __shared__ int deg[BNODES];
    int b = blockIdx.x;
    if (threadIdx.x < BNODES) deg[threadIdx.x] = 0;
    __syncthreads();
    int s = bbcScan[b * NBLK];
    int e_end = (b == nbuck - 1) ? E : bbcScan[(b + 1) * NBLK];
    for (int i = s + threadIdx.x; i < e_end; i += blockDim.x)
        atomicAdd(&deg[stage[i] & (BNODES - 1)], 1);
    __syncthreads();
    int v = b * BNODES + threadIdx.x;
    if (threadIdx.x < BNODES && v < N)
        dinv[v] = rsqrtf((float)deg[threadIdx.x] + 1.0f);
}

// ---------- h1s = (x @ W1) * dinv[v] ----------
__global__ void gemm1_kernel(const float* __restrict__ x, const float* __restrict__ W1,
                             const float* __restrict__ dinv, float* __restrict__ h1s, int N) {
    __shared__ float sW[F_IN * H1];
    for (int i = threadIdx.x; i < F_IN * H1; i += blockDim.x) sW[i] = W1[i];
    __syncthreads();
    int v = blockIdx.x * blockDim.x + threadIdx.x;
    if (v >= N) return;
    float acc[H1];
#pragma unroll
    for (int j = 0; j < H1; ++j) acc[j] = 0.0f;
    const float4* xr = reinterpret_cast<const float4*>(x + (size_t)v * F_IN);
#pragma unroll 8
    for (int k4 = 0; k4 < F_IN / 4; ++k4) {
        float4 xv = xr[k4];
        const float* w = &sW[k4 * 4 * H1];
#pragma unroll
        for (int j = 0; j < H1; ++j) acc[j] += xv.x * w[j];
#pragma unroll
        for (int j = 0; j < H1; ++j) acc[j] += xv.y * w[H1 + j];
#pragma unroll
        for (int j = 0; j < H1; ++j) acc[j] += xv.z * w[2 * H1 + j];
#pragma unroll
        for (int j = 0; j < H1; ++j) acc[j] += xv.w * w[3 * H1 + j];
    }
    float di = dinv[v];
    float4* ho = reinterpret_cast<float4*>(h1s + (size_t)v * H1);
#pragma unroll
    for (int q = 0; q < H1 / 4; ++q) {
        ho[q] = make_float4(acc[q * 4 + 0] * di, acc[q * 4 + 1] * di,
                            acc[q * 4 + 2] * di, acc[q * 4 + 3] * di);
    }
}

// ---------- layer-1 aggregation in LDS + relu + GEMM2 fused ----------
#define AGG1_PAD 17
#define AGG1_TB  512
__global__ __launch_bounds__(AGG1_TB) void agg1_kernel(
        const int* __restrict__ stage, const int* __restrict__ bbcScan,
        int E, int nbuck, const float* __restrict__ h1s,
        const float* __restrict__ dinv, const float* __restrict__ b1,
        const float* __restrict__ W2, float* __restrict__ h2s, int N) {
    __shared__ float agg[BNODES * AGG1_PAD];
    __shared__ float sW[H1 * C2];
    __shared__ float sb[H1];
    for (int i = threadIdx.x; i < BNODES * AGG1_PAD; i += AGG1_TB) agg[i] = 0.0f;
    for (int i = threadIdx.x; i < H1 * C2; i += AGG1_TB) sW[i] = W2[i];
    for (int i = threadIdx.x; i < H1; i += AGG1_TB) sb[i] = b1[i];
    __syncthreads();

    int b = blockIdx.x;
    int base = b * BNODES;
    int s = bbcScan[b * NBLK];
    int e_end = (b == nbuck - 1) ? E : bbcScan[(b + 1) * NBLK];

    const int f  = threadIdx.x & 15;
    const int ns = AGG1_TB >> 4;          // 32 edge slots
    int i = s + (threadIdx.x >> 4);
    // unrolled x4: independent loads for latency hiding
    for (; i + 3 * ns < e_end; i += 4 * ns) {
        int r0 = stage[i];
        int r1 = stage[i + ns];
        int r2 = stage[i + 2 * ns];
        int r3 = stage[i + 3 * ns];
        float v0 = h1s[(size_t)(r0 >> BSHIFT) * H1 + f];
        float v1 = h1s[(size_t)(r1 >> BSHIFT) * H1 + f];
        float v2 = h1s[(size_t)(r2 >> BSHIFT) * H1 + f];
        float v3 = h1s[(size_t)(r3 >> BSHIFT) * H1 + f];
        atomicAdd(&agg[(r0 & (BNODES - 1)) * AGG1_PAD + f], v0);
        atomicAdd(&agg[(r1 & (BNODES - 1)) * AGG1_PAD + f], v1);
        atomicAdd(&agg[(r2 & (BNODES - 1)) * AGG1_PAD + f], v2);
        atomicAdd(&agg[(r3 & (BNODES - 1)) * AGG1_PAD + f], v3);
    }
    for (; i < e_end; i += ns) {
        int rec = stage[i];
        float val = h1s[(size_t)(rec >> BSHIFT) * H1 + f];
        atomicAdd(&agg[(rec & (BNODES - 1)) * AGG1_PAD + f], val);
    }
    __syncthreads();

    // finalize: relu(dinv*(agg + self) + b1), store back to LDS
    for (int vi = threadIdx.x >> 4; vi < BNODES; vi += ns) {
        int v = base + vi;
        if (v < N) {
            float hv = dinv[v] * (agg[vi * AGG1_PAD + f] + h1s[(size_t)v * H1 + f]) + sb[f];
            agg[vi * AGG1_PAD + f] = fmaxf(hv, 0.0f);
        }
    }
    __syncthreads();

    // GEMM2: h2s[v] = (hrelu @ W2) * dinv[v]
    int j = threadIdx.x & 7;
    for (int vi = threadIdx.x >> 3; vi < BNODES; vi += (AGG1_TB >> 3)) {
        int v = base + vi;
        if (v < N) {
            float dot = 0.0f;
#pragma unroll
            for (int k = 0; k < H1; ++k) dot += agg[vi * AGG1_PAD + k] * sW[k * C2 + j];
            h2s[(size_t)v * C2 + j] = dot * dinv[v];
        }
    }
}

// ---------- layer-2 aggregation in LDS + bias + log_softmax fused ----------
#define AGG2_PAD 9
#define AGG2_TB  512
__global__ __launch_bounds__(AGG2_TB) void agg2_kernel(
        const int* __restrict__ stage, const int* __restrict__ bbcScan,
        int E, int nbuck, const float* __restrict__ h2s,
        const float* __restrict__ dinv, const float* __restrict__ b2,
        float* __restrict__ out, int N) {
    __shared__ float agg[BNODES * AGG2_PAD];
    __shared__ float sb[C2];
    for (int i = threadIdx.x; i < BNODES * AGG2_PAD; i += AGG2_TB) agg[i] = 0.0f;
    if (threadIdx.x < C2) sb[threadIdx.x] = b2[threadIdx.x];
    __syncthreads();

    int b = blockIdx.x;
    int base = b * BNODES;
    int s = bbcScan[b * NBLK];
    int e_end = (b == nbuck - 1) ? E : bbcScan[(b + 1) * NBLK];

    const int f  = threadIdx.x & 7;
    const int ns = AGG2_TB >> 3;          // 64 edge slots
    int i = s + (threadIdx.x >> 3);
    for (; i + 3 * ns < e_end; i += 4 * ns) {
        int r0 = stage[i];
        int r1 = stage[i + ns];
        int r2 = stage[i + 2 * ns];
        int r3 = stage[i + 3 * ns];
        float v0 = h2s[(size_t)(r0 >> BSHIFT) * C2 + f];
        float v1 = h2s[(size_t)(r1 >> BSHIFT) * C2 + f];
        float v2 = h2s[(size_t)(r2 >> BSHIFT) * C2 + f];
        float v3 = h2s[(size_t)(r3 >> BSHIFT) * C2 + f];
        atomicAdd(&agg[(r0 & (BNODES - 1)) * AGG2_PAD + f], v0);
        atomicAdd(&agg[(r1 & (BNODES - 1)) * AGG2_PAD + f], v1);
        atomicAdd(&agg[(r2 & (BNODES - 1)) * AGG2_PAD + f], v2);
        atomicAdd(&agg[(r3 & (BNODES - 1)) * AGG2_PAD + f], v3);
    }
    for (; i < e_end; i += ns) {
        int rec = stage[i];
        float val = h2s[(size_t)(rec >> BSHIFT) * C2 + f];
        atomicAdd(&agg[(rec & (BNODES - 1)) * AGG2_PAD + f], val);
    }
    __syncthreads();

    for (int vi = threadIdx.x >> 3; vi < BNODES; vi += ns) {
        int v = base + vi;
        if (v < N) {
            float z = dinv[v] * (agg[vi * AGG2_PAD + f] + h2s[(size_t)v * C2 + f]) + sb[f];
            float m = z;
#pragma unroll
            for (int mask = 1; mask < 8; mask <<= 1)
                m = fmaxf(m, __shfl_xor(m, mask, 8));
            float ex = __expf(z - m);
            float ssum = ex;
#pragma unroll
            for (int mask = 1; mask < 8; mask <<= 1)
                ssum += __shfl_xor(ssum, mask, 8);
            float lse = m + logf(ssum);
            out[(size_t)v * C2 + f] = z - lse;
        }
    }
}

extern "C" void kernel_launch(void* const* d_in, const int* in_sizes, int n_in,
                              void* d_out, int out_size, void* d_ws, size_t ws_size,
                              hipStream_t stream) {
    const float* x  = (const float*)d_in[0];
    const int*   ei = (const int*)d_in[1];
    const float* W1 = (const float*)d_in[2];
    const float* b1 = (const float*)d_in[3];
    const float* W2 = (const float*)d_in[4];
    const float* b2 = (const float*)d_in[5];
    float* out = (float*)d_out;

    const int N = in_sizes[0] / F_IN;
    const int E = in_sizes[1] / 2;
    const int nbuck = (N + BNODES - 1) >> BSHIFT;        // 782
    const int M = nbuck * NBLK;                          // 200192
    const int chunk = (E + NBLK - 1) / NBLK;             // 12500

    // workspace layout (ints/floats, 4B each)
    int*   stage   = (int*)d_ws;                         // E
    int*   bbc     = stage + E;                          // M
    int*   bbcScan = bbc + M;                            // M
    int*   bsum    = bbcScan + M;                        // 1024
    int*   boff    = bsum + 1024;                        // 1024
    float* dinv    = (float*)(boff + 1024);              // N
    float* h1s     = dinv + N;                           // 16N
    float* h2s     = h1s + (size_t)16 * N;               // 8N

    const int TB = 256;
    const int scanBlocks = (M + 255) / 256;              // = nbuck

    binA_kernel<<<NBLK, TB, 0, stream>>>(ei + E, E, chunk, nbuck, bbc);
    scanA_kernel<<<scanBlocks, TB, 0, stream>>>(bbc, M, bbcScan, bsum);
    scanB_kernel<<<1, 1024, 0, stream>>>(bsum, boff, scanBlocks);
    scanC_kernel<<<scanBlocks, TB, 0, stream>>>(bbcScan, boff, M);
    binScatter_kernel<<<NBLK, TB, 0, stream>>>(ei, E, chunk, nbuck, bbcScan, stage);
    degdinv_kernel<<<nbuck, TB, 0, stream>>>(stage, bbcScan, E, nbuck, dinv, N);
    gemm1_kernel<<<(N + TB - 1) / TB, TB, 0, stream>>>(x, W1, dinv, h1s, N);
    agg1_kernel<<<nbuck, AGG1_TB, 0, stream>>>(stage, bbcScan, E, nbuck, h1s, dinv, b1, W2, h2s, N);
    agg2_kernel<<<nbuck, AGG2_TB, 0, stream>>>(stage, bbcScan, E, nbuck, h2s, dinv, b2, out, N);
}